// Round 15
// baseline (27.307 us; speedup 1.0000x reference)
//
#include <hip/hip_runtime.h>

#define IW 512
#define IH 512
#define NPIX (IH * IW)
#define NK 6            // steps 1..6 (step 0 is exact identity)
#define GROUPS 8        // group == bid&7 == XCD -> 3 planes per XCD, L2-resident
#define PPT 3
#define WW 160          // per-step window width in floats (max needed: 155)

typedef float f4v __attribute__((ext_vector_type(4)));

// Drain all LDS ops of this wave + compiler memory fence. Global loads
// (vmcnt) are unaffected -- prefetches stay in flight across this.
#define FENCE() asm volatile("s_waitcnt lgkmcnt(0)" ::: "memory")

// issue 12 window loads (stager lanes) + 2 identity loads for one plane
#define STAGE_LOAD(bp, iA, iB) do {                              \
    const float* __restrict__ _b = (bp);                         \
    if (stager) {                                                \
        _Pragma("unroll")                                        \
        for (int k = 0; k < NK; ++k) {                           \
            const int cc = min(max(wb[k] + sl4, 0), IW - 4);     \
            va[k] = *(const f4v*)(_b + rowA[k] + cc);            \
            vb[k] = *(const f4v*)(_b + rowA[k] + IW + cc);       \
        }                                                        \
    }                                                            \
    iA = _b[idoff];                                              \
    iB = _b[idoff + 64];                                         \
} while (0)

// vertical lerp + OOB-column zeroing (edge waves only), publish into Wp
#define LERP_WRITE(Wp) do {                                      \
    if (stager) {                                                \
        _Pragma("unroll")                                        \
        for (int k = 0; k < NK; ++k) {                           \
            f4v v = t0[k] * va[k] + t1[k] * vb[k];               \
            if (edgemask & (1 << k)) {                           \
                const int ub = wb[k] + sl4;                      \
                v.x = (ub     >= 0 && ub     < IW) ? v.x : 0.0f; \
                v.y = (ub + 1 >= 0 && ub + 1 < IW) ? v.y : 0.0f; \
                v.z = (ub + 2 >= 0 && ub + 2 < IW) ? v.z : 0.0f; \
                v.w = (ub + 3 >= 0 && ub + 3 < IW) ? v.w : 0.0f; \
            }                                                    \
            *(f4v*)&(Wp)[k * WW + sl4] = v;                      \
        }                                                        \
    }                                                            \
} while (0)

// horizontal lerp for the wave's 2 owned pixels per lane from Wp, NT store.
// No clamps: every tap col (incl. OOB) is a staged slot (OOB -> 0).
#define COMPUTE_STORE(Wp, cA, cB, op) do {                       \
    float aA = (cA) * (1.0f / 7.0f);                             \
    float aB = (cB) * (1.0f / 7.0f);                             \
    _Pragma("unroll")                                            \
    for (int k = 0; k < NK; ++k) {                               \
        const float v0A = (Wp)[offA[k]];                         \
        const float v1A = (Wp)[offA[k] + 1];                     \
        const float v0B = (Wp)[offB[k]];                         \
        const float v1B = (Wp)[offB[k] + 1];                     \
        aA = fmaf(wxA[k], v1A - v0A, aA + v0A);                  \
        aB = fmaf(wxB[k], v1B - v0B, aB + v0B);                  \
    }                                                            \
    float* _o = (op);                                            \
    __builtin_nontemporal_store(aA, _o);                         \
    __builtin_nontemporal_store(aB, _o + 64);                    \
} while (0)

__global__ __launch_bounds__(256, 4) void zoomblur_kernel(
    const float* __restrict__ img,
    const float* __restrict__ zoomf,
    float* __restrict__ out)
{
    __shared__ float lds[4][2][NK * WW];   // 30 KB: 2 window sets per wave

    const int tid   = threadIdx.x;
    const int lane  = tid & 63;
    const int wv    = tid >> 6;             // wave id = column chunk
    const int bid   = blockIdx.x;
    const int group = bid & (GROUPS - 1);   // == XCD (round-robin dispatch)
    const int y     = bid >> 3;             // one output row per block
    const int cb0   = wv << 7;              // wave owns cols [cb0, cb0+128)

    const float zf = 0.85f + 0.30f * zoomf[0];
    const float dz = zf - 1.0f;
    const float yf = (float)y - 256.0f;

    float invs[NK];
#pragma unroll
    for (int s = 1; s <= NK; ++s)
        invs[s - 1] = __builtin_amdgcn_rcpf(fmaf((float)s * (1.0f / 6.0f), dz, 1.0f));

    // ---- wave-uniform per step: window base, source rows, row weights (x1/7),
    //      edge flag (window touches outside [0,512)) ----
    int   wb[NK], rowA[NK];
    float t0[NK], t1[NK];
    int   edgemask = 0;
#pragma unroll
    for (int k = 0; k < NK; ++k) {
        const float inv = invs[k];
        wb[k] = ((int)floorf(fmaf((float)cb0 - 256.0f, inv, 256.0f))) & ~3;
        if (wb[k] < 0 || wb[k] + WW > IW) edgemask |= (1 << k);
        const float ysv = fmaf(yf, inv, 256.0f);
        const float fy  = floorf(ysv);
        const float wy  = ysv - fy;
        const int y0 = (int)fy;
        const int yb = min(max(y0, 0), IH - 2);
        const float ta = (yb == y0 ? 1.0f - wy : 0.0f) + (yb == y0 + 1 ? wy : 0.0f);
        const float tb = (yb + 1 == y0 ? 1.0f - wy : 0.0f) + (yb + 1 == y0 + 1 ? wy : 0.0f);
        t0[k] = ta * (1.0f / 7.0f);     // staged lines carry the /7
        t1[k] = tb * (1.0f / 7.0f);
        rowA[k] = yb * IW;
    }

    // ---- per-lane column taps: pixels xA = cb0+lane, xB = xA+64.
    //      Window covers [floor(xs(cb0)), floor(xs(cb0+127))+1] (monotone,
    //      same inv; WW=160 >= worst-case 155-slot span) -> no clamps. ----
    int   offA[NK], offB[NK];
    float wxA[NK], wxB[NK];
    const float xfA = (float)(cb0 + lane) - 256.0f;
#pragma unroll
    for (int k = 0; k < NK; ++k) {
        const float inv = invs[k];
        const float xsA = fmaf(xfA, inv, 256.0f);
        const float xsB = fmaf(xfA + 64.0f, inv, 256.0f);
        const float fxA = floorf(xsA), fxB = floorf(xsB);
        wxA[k] = xsA - fxA;
        wxB[k] = xsB - fxB;
        offA[k] = (int)fxA - wb[k] + k * WW;
        offB[k] = (int)fxB - wb[k] + k * WW;
    }

    float* __restrict__ W0 = &lds[wv][0][0];
    float* __restrict__ W1 = &lds[wv][1][0];
    const bool stager = lane < (WW / 4);    // 40 staging lanes per wave
    const int  sl4    = lane << 2;          // f4-slot base (floats)

    const int idoff = y * IW + cb0 + lane;
    const size_t pbase = (size_t)(group * PPT) * NPIX;
    const float* __restrict__ ib = img + pbase;
    float* __restrict__ ob = out + pbase + idoff;

    f4v va[NK], vb[NK];
    float idA0, idB0, idA1, idB1, idA2, idB2;

    // ---- barrier-free, fenced, double-buffered pipeline ----
    STAGE_LOAD(ib, idA0, idB0);                 // plane 0
    LERP_WRITE(W0);                             // publish p0 -> buf0
    STAGE_LOAD(ib + NPIX, idA1, idB1);          // plane 1 in flight
    LERP_WRITE(W1);                             // publish p1 -> buf1
    FENCE();                                    // p0/p1 writes committed

    COMPUTE_STORE(W0, idA0, idB0, ob);          // read buf0 (p0)
    FENCE();                                    // buf0 reads drained (WAR)
    STAGE_LOAD(ib + 2 * NPIX, idA2, idB2);      // plane 2 in flight
    LERP_WRITE(W0);                             // publish p2 -> buf0
    FENCE();                                    // p2 writes committed

    COMPUTE_STORE(W1, idA1, idB1, ob + NPIX);   // read buf1 (p1)
    COMPUTE_STORE(W0, idA2, idB2, ob + 2 * NPIX); // read buf0 (p2)
}

extern "C" void kernel_launch(void* const* d_in, const int* in_sizes, int n_in,
                              void* d_out, int out_size, void* d_ws, size_t ws_size,
                              hipStream_t stream) {
    const float* img  = (const float*)d_in[0];
    const float* zoom = (const float*)d_in[1];
    float* out = (float*)d_out;

    dim3 block(256);
    dim3 grid(IH * GROUPS);      // 4096 blocks; bid&7 == XCD, 3 planes each
    zoomblur_kernel<<<grid, block, 0, stream>>>(img, zoom, out);
}

// Round 16
// 23.576 us; speedup vs baseline: 1.1582x; 1.1582x over previous
//
#include <hip/hip_runtime.h>

#define IW 512
#define IH 512
#define NPIX (IH * IW)
#define NK 6            // steps 1..6 (step 0 is exact identity)
#define GROUPS 8        // group == bid&7 == XCD -> 3 planes per XCD, L2-resident
#define PPT 3
#define LROW 520        // pair-slots per line: 4 guard + 512 data + 4 guard
#define GOFF 4

typedef float f4v __attribute__((ext_vector_type(4)));
typedef unsigned int u4v __attribute__((ext_vector_type(4)));

// pair layout: lo16 = bf16(v[c]), hi16 = bf16(v[c+1])  (truncation; tol 2e-2)
__device__ __forceinline__ float bf16lo(unsigned p) { return __uint_as_float(p << 16); }
__device__ __forceinline__ float bf16hi(unsigned p) { return __uint_as_float(p & 0xffff0000u); }
__device__ __forceinline__ unsigned packpair(float lo, float hi) {
    // D.b01 = top16(lo), D.b23 = top16(hi)  -> v_perm_b32
    return __builtin_amdgcn_perm(__float_as_uint(hi), __float_as_uint(lo), 0x07060302u);
}

// issue 6 f4 row loads + edge-halo loads + 2 identity loads for one plane
#define STAGE_LOAD(base_, iA_, iB_) do {                         \
    const float* __restrict__ _b = (base_);                      \
    _Pragma("unroll")                                            \
    for (int j = 0; j < 3; ++j) {                                \
        va[j] = *(const f4v*)(_b + rows[j] + cq);                \
        vb[j] = *(const f4v*)(_b + rows[j] + IW + cq);           \
        ha[j] = edge63 ? _b[rows[j] + 256]      : 0.0f;          \
        hb[j] = edge63 ? _b[rows[j] + IW + 256] : 0.0f;          \
    }                                                            \
    iA_ = _b[idoff];                                             \
    iB_ = _b[idoff + 256];                                       \
} while (0)

// vertical lerp, bf16 pair-pack (overlapping pairs via shfl halo), publish
#define LERP_WRITE(B) do {                                       \
    _Pragma("unroll")                                            \
    for (int j = 0; j < 3; ++j) {                                \
        const f4v L = t0s[j] * va[j] + t1s[j] * vb[j];           \
        const float nv = __shfl_down(L.x, 1);                    \
        const float hv = t0s[j] * ha[j] + t1s[j] * hb[j];        \
        const float v4 = lane63 ? (edge63 ? hv : 0.0f) : nv;     \
        u4v p;                                                   \
        p.x = packpair(L.x, L.y);                                \
        p.y = packpair(L.y, L.z);                                \
        p.z = packpair(L.z, L.w);                                \
        p.w = packpair(L.w, v4);                                 \
        *(u4v*)&rrow[B][wofs[j]] = p;                            \
        if (lane0q)   /* left-guard pair for col -1: {0, v0} */  \
            rrow[B][lgofs[j]] = __float_as_uint(L.x) & 0xffff0000u; \
    }                                                            \
} while (0)

// horizontal lerp: ONE ds_read_b32 per (pixel, step); NT store
#define COMPUTE_STORE(B, cA_, cB_, op_) do {                     \
    float aA = (cA_) * (1.0f / 7.0f);                            \
    float aB = (cB_) * (1.0f / 7.0f);                            \
    _Pragma("unroll")                                            \
    for (int k = 0; k < NK; ++k) {                               \
        const unsigned pa = rrow[B][k * LROW + colA[k]];         \
        const unsigned pb = rrow[B][k * LROW + colB[k]];         \
        const float v0a = bf16lo(pa), v1a = bf16hi(pa);          \
        const float v0b = bf16lo(pb), v1b = bf16hi(pb);          \
        aA = fmaf(wxA[k], v1a - v0a, aA + v0a);                  \
        aB = fmaf(wxB[k], v1b - v0b, aB + v0b);                  \
    }                                                            \
    float* _o = (op_);                                           \
    __builtin_nontemporal_store(aA, _o);                         \
    __builtin_nontemporal_store(aB, _o + 256);                   \
} while (0)

__global__ __launch_bounds__(256, 8) void zoomblur_kernel(
    const float* __restrict__ img,
    const float* __restrict__ zoomf,
    float* __restrict__ out)
{
    __shared__ unsigned int rrow[2][NK * LROW];   // 25 KB: dbuf 6 pair-lines

    const int tid   = threadIdx.x;
    const int bid   = blockIdx.x;
    const int group = bid & (GROUPS - 1);   // == XCD (round-robin dispatch)
    const int y     = bid >> 3;             // one output row per block

    const float zf = 0.85f + 0.30f * zoomf[0];
    const float dz = zf - 1.0f;
    const float yf  = (float)y - 256.0f;
    // split-pixel ownership: x = tid and x = tid+256
    const float xfA = (float)tid - 256.0f;
    const float xfB = (float)tid;

    float invs[NK];
#pragma unroll
    for (int s = 1; s <= NK; ++s)
        invs[s - 1] = __builtin_amdgcn_rcpf(fmaf((float)s * (1.0f / 6.0f), dz, 1.0f));

    // per-thread column taps; guard-zero: clamp into zeroed guard slots.
    // pair trick: tap pair (c, c+1) lives entirely in pair-slot c.
    int   colA[NK], colB[NK];
    float wxA[NK], wxB[NK];
#pragma unroll
    for (int k = 0; k < NK; ++k) {
        const float inv = invs[k];
        const float xsA = fmaf(xfA, inv, 256.0f);
        const float xsB = fmaf(xfB, inv, 256.0f);
        const float fxA = floorf(xsA);
        const float fxB = floorf(xsB);
        wxA[k] = xsA - fxA;
        wxB[k] = xsB - fxB;
        colA[k] = GOFF + min(max((int)fxA, -2), IW);   // slots 2..516
        colB[k] = GOFF + min(max((int)fxB, -2), IW);
    }

    // staging role: thread stages col-quad cq of lines {sbase, sbase+2, sbase+4}
    const int  sbase  = tid >> 7;            // 0 or 1
    const int  cq     = (tid & 127) << 2;    // 0..508
    const bool lane63 = (tid & 63) == 63;
    const bool edge63 = (tid & 127) == 63;   // halo col 256 needed
    const bool lane0q = (tid & 127) == 0;    // writes left-guard pair

    float t0s[3], t1s[3];
    int   rows[3], wofs[3], lgofs[3];
#pragma unroll
    for (int j = 0; j < 3; ++j) {
        const int k = sbase + 2 * j;
        const float inv = invs[k];
        const float ysv = fmaf(yf, inv, 256.0f);
        const float fy  = floorf(ysv);
        const float wy  = ysv - fy;
        const int y0 = (int)fy;
        const int yb = min(max(y0, 0), IH - 2);
        const float ta = (yb == y0 ? 1.0f - wy : 0.0f) + (yb == y0 + 1 ? wy : 0.0f);
        const float tb = (yb + 1 == y0 ? 1.0f - wy : 0.0f) + (yb + 1 == y0 + 1 ? wy : 0.0f);
        t0s[j] = ta * (1.0f / 7.0f);        // staged lines carry the /7
        t1s[j] = tb * (1.0f / 7.0f);
        rows[j]  = yb * IW;
        wofs[j]  = k * LROW + GOFF + cq;
        lgofs[j] = k * LROW + 3;            // pair for col -1
    }

    // zero guard slots of both buffers once (slot 3 is rewritten per plane)
    if (tid < 96) {
        const int line = tid >> 3;              // 0..11
        const int j    = tid & 7;
        const int slot = (j < 4) ? j : 512 + j; // 0..3, 516..519
        const int buf  = line >= NK;
        const int l    = buf ? line - NK : line;
        rrow[buf][l * LROW + slot] = 0u;
    }

    const int idoff = y * IW + tid;
    const size_t pbase = (size_t)(group * PPT) * NPIX;
    const float* __restrict__ ib = img + pbase;
    float* __restrict__       ob = out + pbase;

    f4v  va[3], vb[3];
    float ha[3], hb[3];
    float idA0, idB0, idA1, idB1, idA2, idB2;

    // ---- R9 pipeline: stage p0 -> [compute p | prefetch p+1] ----
    STAGE_LOAD(ib, idA0, idB0);           // plane 0
    LERP_WRITE(0);
    __syncthreads();                      // buf0 ready
    STAGE_LOAD(ib + NPIX, idA1, idB1);    // plane-1 loads fly over compute 0

    COMPUTE_STORE(0, idA0, idB0, ob + idoff);
    LERP_WRITE(1);                        // consume plane-1 loads
    __syncthreads();                      // buf1 ready; buf0 reads done
    STAGE_LOAD(ib + 2 * NPIX, idA2, idB2);

    COMPUTE_STORE(1, idA1, idB1, ob + NPIX + idoff);
    LERP_WRITE(0);                        // safe: buf0 reads finished pre-barrier
    __syncthreads();                      // buf0 ready again

    COMPUTE_STORE(0, idA2, idB2, ob + 2 * NPIX + idoff);
}

extern "C" void kernel_launch(void* const* d_in, const int* in_sizes, int n_in,
                              void* d_out, int out_size, void* d_ws, size_t ws_size,
                              hipStream_t stream) {
    const float* img  = (const float*)d_in[0];
    const float* zoom = (const float*)d_in[1];
    float* out = (float*)d_out;

    dim3 block(256);
    dim3 grid(IH * GROUPS);      // 4096 blocks; bid&7 == XCD, 3 planes each
    zoomblur_kernel<<<grid, block, 0, stream>>>(img, zoom, out);
}